// Round 3
// baseline (230.936 us; speedup 1.0000x reference)
//
#include <hip/hip_runtime.h>
#include <hip/hip_bf16.h>
#include <math.h>

#define NN 8192
#define L2E 1.44269504088896340736f
#define TWO_PI 6.28318530717958647693f

typedef _Float16 h8 __attribute__((ext_vector_type(8)));
typedef _Float16 h4 __attribute__((ext_vector_type(4)));
typedef float f32x4 __attribute__((ext_vector_type(4)));

#define MFMA16(A, B, C) __builtin_amdgcn_mfma_f32_16x16x32_f16(A, B, C, 0, 0, 0)

// ---------------------------------------------------------------------------
// prep: eta_s = eta*s, phi_s = phi*s with s = sqrt(alpha*log2e);
// H1 = relu(x@W1+b1) f32 row-major + f16 transposed [64][NN]. 32 rows/block.
// ---------------------------------------------------------------------------
__global__ __launch_bounds__(256) void prep_kernel(
    const float* __restrict__ x, const float* __restrict__ alpha,
    const float* __restrict__ W1, const float* __restrict__ b1,
    float* __restrict__ eta_s, float* __restrict__ phi_s,
    float* __restrict__ H1, _Float16* __restrict__ HT1,
    float* __restrict__ svec)
{
  __shared__ float sW[448];
  __shared__ float sb[64];
  __shared__ float T[32][65];
  const int t = threadIdx.x;
  if (blockIdx.x == 0 && t < 64) svec[t] = 0.f;
  for (int k = t; k < 448; k += 256) sW[k] = W1[k];
  if (t < 64) sb[t] = b1[t];
  const float s = sqrtf(alpha[0] * L2E);
  const int i0 = blockIdx.x * 32;
  const int r = t >> 3, q = t & 7;
  const int i = i0 + r;
  float xv[7];
#pragma unroll
  for (int k = 0; k < 7; k++) xv[k] = x[i * 7 + k];
  if (q == 0) { eta_s[i] = xv[1] * s; phi_s[i] = xv[2] * s; }
  __syncthreads();
#pragma unroll
  for (int c = 0; c < 8; c++) {
    const int n = q * 8 + c;
    float hv = sb[n];
#pragma unroll
    for (int k = 0; k < 7; k++) hv = fmaf(xv[k], sW[k * 64 + n], hv);
    T[r][n] = fmaxf(hv, 0.f);
  }
  __syncthreads();
  for (int e = t; e < 2048; e += 256) H1[i0 * 64 + e] = T[e >> 6][e & 63];
  const int n = t >> 2, sg = (t & 3) * 8;
  h8 v;
#pragma unroll
  for (int ss = 0; ss < 8; ss++) v[ss] = (_Float16)T[sg + ss][n];
  *(h8*)(HT1 + (size_t)n * NN + i0 + sg) = v;
}

// ---------------------------------------------------------------------------
// attn: 32-row tile per wave-quad; j split 8 ways across blocks (grid 2048),
// contiguous 256-wide j-range per wave (8 iters of 32 j). Scores in MFMA
// A-layout; HT f16 16B loads give B-frags. 4 waves reduce in LDS ->
// ONE Ypart partial per block (8 partials total).
// ---------------------------------------------------------------------------
template <bool NEED_L>
__global__ __launch_bounds__(256, 6) void attn_pass(
    const float* __restrict__ eta_s, const float* __restrict__ phi_s,
    const _Float16* __restrict__ HT, const float* __restrict__ alpha,
    float* __restrict__ Ypart, float* __restrict__ lpart)
{
  const int tid = threadIdx.x;
  const int w = tid >> 6;
  const int lane = tid & 63;
  const int m = lane & 15;
  const int g = lane >> 4;
  const int tile = blockIdx.x >> 3;
  const int part = blockIdx.x & 7;
  const int i0 = tile << 5;
  const float Cs = TWO_PI * sqrtf(alpha[0] * L2E);
  const float et0 = eta_s[i0 + m],      ph0 = phi_s[i0 + m];
  const float et1 = eta_s[i0 + 16 + m], ph1 = phi_s[i0 + 16 + m];

  f32x4 a00 = {0,0,0,0}, a01 = {0,0,0,0}, a02 = {0,0,0,0}, a03 = {0,0,0,0};
  f32x4 a10 = {0,0,0,0}, a11 = {0,0,0,0}, a12 = {0,0,0,0}, a13 = {0,0,0,0};
  float l0 = 0.f, l1 = 0.f;

  const int jb = part * 1024 + w * 256 + g * 8;
  const float* ep  = eta_s + jb;
  const float* php = phi_s + jb;
  const _Float16* h0p = HT + (size_t)(0 * 16 + m) * NN + jb;
  const _Float16* h1p = HT + (size_t)(1 * 16 + m) * NN + jb;
  const _Float16* h2p = HT + (size_t)(2 * 16 + m) * NN + jb;
  const _Float16* h3p = HT + (size_t)(3 * 16 + m) * NN + jb;

  float4 e0 = *(const float4*)ep,  e1 = *(const float4*)(ep + 4);
  float4 p0 = *(const float4*)php, p1 = *(const float4*)(php + 4);
  h8 b0 = *(const h8*)h0p, b1 = *(const h8*)h1p;
  h8 b2 = *(const h8*)h2p, b3 = *(const h8*)h3p;

  union AF { h8 v; decltype(__builtin_amdgcn_cvt_pkrtz(0.f, 0.f)) p[4]; };

  for (int it = 0; it < 8; ++it) {
    const float ea[8] = {e0.x, e0.y, e0.z, e0.w, e1.x, e1.y, e1.z, e1.w};
    const float pa[8] = {p0.x, p0.y, p0.z, p0.w, p1.x, p1.y, p1.z, p1.w};
    // issue next eta/phi loads
    ep += 32; php += 32;
    e0 = *(const float4*)ep;  e1 = *(const float4*)(ep + 4);
    p0 = *(const float4*)php; p1 = *(const float4*)(php + 4);

    AF af0, af1;
#pragma unroll
    for (int tt = 0; tt < 8; tt += 2) {
      float P[4];
#pragma unroll
      for (int u = 0; u < 2; ++u) {
        {
          const float dp = ph0 - pa[tt + u];
          const float wr = fminf(fabsf(dp), Cs - fabsf(dp));
          const float de = et0 - ea[tt + u];
          const float r2 = fmaf(de, de, wr * wr);
          const float a  = __builtin_amdgcn_exp2f(-r2);
          const float pv = __builtin_amdgcn_exp2f(fmaf(a, L2E, -L2E));
          if constexpr (NEED_L) l0 += pv;
          P[u] = pv;
        }
        {
          const float dp = ph1 - pa[tt + u];
          const float wr = fminf(fabsf(dp), Cs - fabsf(dp));
          const float de = et1 - ea[tt + u];
          const float r2 = fmaf(de, de, wr * wr);
          const float a  = __builtin_amdgcn_exp2f(-r2);
          const float pv = __builtin_amdgcn_exp2f(fmaf(a, L2E, -L2E));
          if constexpr (NEED_L) l1 += pv;
          P[2 + u] = pv;
        }
      }
      af0.p[tt >> 1] = __builtin_amdgcn_cvt_pkrtz(P[0], P[1]);
      af1.p[tt >> 1] = __builtin_amdgcn_cvt_pkrtz(P[2], P[3]);
    }
    a00 = MFMA16(af0.v, b0, a00); a01 = MFMA16(af0.v, b1, a01);
    a02 = MFMA16(af0.v, b2, a02); a03 = MFMA16(af0.v, b3, a03);
    a10 = MFMA16(af1.v, b0, a10); a11 = MFMA16(af1.v, b1, a11);
    a12 = MFMA16(af1.v, b2, a12); a13 = MFMA16(af1.v, b3, a13);
    // issue next B-frag loads
    h0p += 32; h1p += 32; h2p += 32; h3p += 32;
    b0 = *(const h8*)h0p; b1 = *(const h8*)h1p;
    b2 = *(const h8*)h2p; b3 = *(const h8*)h3p;
  }

  // 4-wave LDS reduction -> single partial. D layout: col=lane&15,
  // row=(lane>>4)*4+reg.
  __shared__ float red[2][32][66];
  __shared__ float lred2[2][4][32];
  const int h = w >> 1;
  if ((w & 1) == 0) {
#pragma unroll
    for (int r = 0; r < 4; ++r) {
      red[h][g * 4 + r][m]      = a00[r]; red[h][g * 4 + r][16 + m] = a01[r];
      red[h][g * 4 + r][32 + m] = a02[r]; red[h][g * 4 + r][48 + m] = a03[r];
      red[h][16 + g * 4 + r][m]      = a10[r]; red[h][16 + g * 4 + r][16 + m] = a11[r];
      red[h][16 + g * 4 + r][32 + m] = a12[r]; red[h][16 + g * 4 + r][48 + m] = a13[r];
    }
    if constexpr (NEED_L) { lred2[h][g][m] = l0; lred2[h][g][16 + m] = l1; }
  }
  __syncthreads();
  if (w & 1) {
#pragma unroll
    for (int r = 0; r < 4; ++r) {
      red[h][g * 4 + r][m]      += a00[r]; red[h][g * 4 + r][16 + m] += a01[r];
      red[h][g * 4 + r][32 + m] += a02[r]; red[h][g * 4 + r][48 + m] += a03[r];
      red[h][16 + g * 4 + r][m]      += a10[r]; red[h][16 + g * 4 + r][16 + m] += a11[r];
      red[h][16 + g * 4 + r][32 + m] += a12[r]; red[h][16 + g * 4 + r][48 + m] += a13[r];
    }
    if constexpr (NEED_L) { lred2[h][g][m] += l0; lred2[h][g][16 + m] += l1; }
  }
  __syncthreads();
#pragma unroll
  for (int k = 0; k < 8; ++k) {
    const int e = tid + k * 256;
    Ypart[((size_t)part * NN + i0 + (e >> 6)) * 64 + (e & 63)] =
        red[0][e >> 6][e & 63] + red[1][e >> 6][e & 63];
  }
  if constexpr (NEED_L) {
    if (tid < 32) {
      float s = 0.f;
#pragma unroll
      for (int hh = 0; hh < 2; ++hh)
#pragma unroll
        for (int gg = 0; gg < 4; ++gg) s += lred2[hh][gg][tid];
      lpart[(size_t)part * NN + i0 + tid] = s;
    }
  }
}

// ---------------------------------------------------------------------------
// mid: U = sum(Ypart)/l + H1 ; Z = relu(U@wt1+bs1) ; H2 = relu(Z@W2+b2)
// 16 rows/block, grid 512, f32x4 LDS weight reads.
// ---------------------------------------------------------------------------
__global__ __launch_bounds__(256) void mid_kernel(
    const float* __restrict__ Yp, const float* __restrict__ lp,
    const float* __restrict__ H1, const float* __restrict__ wt1,
    const float* __restrict__ bs1, const float* __restrict__ W2,
    const float* __restrict__ b2, float* __restrict__ H2,
    _Float16* __restrict__ HT2)
{
  __shared__ float sA[64][68];
  __shared__ float sB[64][68];
  __shared__ float U[16][65];
  __shared__ float sb2v[64];
  const int t = threadIdx.x;
  for (int e = t; e < 4096; e += 256) {
    sA[e >> 6][e & 63] = wt1[e];
    sB[e >> 6][e & 63] = W2[e];
  }
  if (t < 64) sb2v[t] = b2[t];
  const float bsv = bs1[0];
  const int i0 = blockIdx.x * 16;
  const int r = t >> 4, q = t & 15;
  const int i = i0 + r;
  float l = 0.f;
#pragma unroll
  for (int p = 0; p < 8; ++p) l += lp[(size_t)p * NN + i];
  const float rl = 1.0f / l;
  f32x4 ya = {0, 0, 0, 0};
#pragma unroll
  for (int p = 0; p < 8; ++p)
    ya += *(const f32x4*)(Yp + ((size_t)p * NN + i) * 64 + q * 4);
  const f32x4 h1 = *(const f32x4*)(H1 + (size_t)i * 64 + q * 4);
#pragma unroll
  for (int c = 0; c < 4; ++c) U[r][q * 4 + c] = fmaf(ya[c], rl, h1[c]);
  __syncthreads();
  float z[4];
#pragma unroll
  for (int c = 0; c < 4; ++c) z[c] = bsv;
  for (int k = 0; k < 64; ++k) {
    const float uk = U[r][k];
    const f32x4 sa = *(const f32x4*)&sA[k][q * 4];
#pragma unroll
    for (int c = 0; c < 4; ++c) z[c] = fmaf(uk, sa[c], z[c]);
  }
  __syncthreads();
#pragma unroll
  for (int c = 0; c < 4; ++c) U[r][q * 4 + c] = fmaxf(z[c], 0.f);
  __syncthreads();
  float hv[4];
#pragma unroll
  for (int c = 0; c < 4; ++c) hv[c] = sb2v[q * 4 + c];
  for (int k = 0; k < 64; ++k) {
    const float uk = U[r][k];
    const f32x4 sb4 = *(const f32x4*)&sB[k][q * 4];
#pragma unroll
    for (int c = 0; c < 4; ++c) hv[c] = fmaf(uk, sb4[c], hv[c]);
  }
  __syncthreads();
#pragma unroll
  for (int c = 0; c < 4; ++c) U[r][q * 4 + c] = fmaxf(hv[c], 0.f);
  __syncthreads();
  for (int e = t; e < 1024; e += 256) H2[i0 * 64 + e] = U[e >> 6][e & 63];
  const int n = t >> 2, sg = (t & 3) * 4;
  h4 v;
#pragma unroll
  for (int ss = 0; ss < 4; ss++) v[ss] = (_Float16)U[sg + ss][n];
  *(h4*)(HT2 + (size_t)n * NN + i0 + sg) = v;
}

// ---------------------------------------------------------------------------
// final: V = relu((sum(Ypart)/l + H2)@wt2 + bs2); column sums -> atomicAdd.
// 16 rows/block, grid 512.
// ---------------------------------------------------------------------------
__global__ __launch_bounds__(256) void final_kernel(
    const float* __restrict__ Yp, const float* __restrict__ lp,
    const float* __restrict__ H2, const float* __restrict__ wt2,
    const float* __restrict__ bs2, float* __restrict__ svec)
{
  __shared__ float sA[64][68];
  __shared__ float U[16][65];
  __shared__ float cred[4][64];
  const int t = threadIdx.x;
  for (int e = t; e < 4096; e += 256) sA[e >> 6][e & 63] = wt2[e];
  const float bsv = bs2[0];
  const int i0 = blockIdx.x * 16;
  const int r = t >> 4, q = t & 15;
  const int i = i0 + r;
  float l = 0.f;
#pragma unroll
  for (int p = 0; p < 8; ++p) l += lp[(size_t)p * NN + i];
  const float rl = 1.0f / l;
  f32x4 ya = {0, 0, 0, 0};
#pragma unroll
  for (int p = 0; p < 8; ++p)
    ya += *(const f32x4*)(Yp + ((size_t)p * NN + i) * 64 + q * 4);
  const f32x4 h2 = *(const f32x4*)(H2 + (size_t)i * 64 + q * 4);
#pragma unroll
  for (int c = 0; c < 4; ++c) U[r][q * 4 + c] = fmaf(ya[c], rl, h2[c]);
  __syncthreads();
  float z[4];
#pragma unroll
  for (int c = 0; c < 4; ++c) z[c] = bsv;
  for (int k = 0; k < 64; ++k) {
    const float uk = U[r][k];
    const f32x4 sa = *(const f32x4*)&sA[k][q * 4];
#pragma unroll
    for (int c = 0; c < 4; ++c) z[c] = fmaf(uk, sa[c], z[c]);
  }
  __syncthreads();
#pragma unroll
  for (int c = 0; c < 4; ++c) U[r][q * 4 + c] = fmaxf(z[c], 0.f);
  __syncthreads();
  const int col = t & 63, rg = t >> 6;
  float ps = 0.f;
#pragma unroll
  for (int rr = 0; rr < 4; rr++) ps += U[rg * 4 + rr][col];
  cred[rg][col] = ps;
  __syncthreads();
  if (t < 64)
    atomicAdd(svec + t, cred[0][t] + cred[1][t] + cred[2][t] + cred[3][t]);
}

__global__ void out_kernel(const float* __restrict__ svec,
                           const float* __restrict__ Wl,
                           const float* __restrict__ bl,
                           float* __restrict__ out)
{
  const int t = threadIdx.x;  // 64 threads
  float v = svec[t] * Wl[t];
#pragma unroll
  for (int off = 32; off > 0; off >>= 1) v += __shfl_down(v, off);
  if (t == 0) {
    const float logit = v + bl[0];
    out[0] = 1.0f / (1.0f + __builtin_amdgcn_exp2f(-logit * L2E));
  }
}

extern "C" void kernel_launch(void* const* d_in, const int* in_sizes, int n_in,
                              void* d_out, int out_size, void* d_ws,
                              size_t ws_size, hipStream_t stream)
{
  const float* x     = (const float*)d_in[0];
  const float* alpha = (const float*)d_in[1];
  const float* W1    = (const float*)d_in[2];
  const float* b1    = (const float*)d_in[3];
  const float* wt1   = (const float*)d_in[4];
  const float* bs1   = (const float*)d_in[5];
  const float* W2    = (const float*)d_in[6];
  const float* b2    = (const float*)d_in[7];
  const float* wt2   = (const float*)d_in[8];
  const float* bs2   = (const float*)d_in[9];
  const float* Wl    = (const float*)d_in[10];
  const float* bl    = (const float*)d_in[11];
  float* out = (float*)d_out;

  char* ws = (char*)d_ws;
  size_t off = 0;
  auto alloc = [&](size_t bytes) {
    void* p = ws + off;
    off = (off + bytes + 255) & ~(size_t)255;
    return p;
  };
  float* eta_s = (float*)alloc(NN * 4 + 256);       // +over-read pad
  float* phi_s = (float*)alloc(NN * 4 + 256);
  float* H1    = (float*)alloc((size_t)NN * 64 * 4);
  float* H2    = (float*)alloc((size_t)NN * 64 * 4);
  float* Ypart = (float*)alloc((size_t)8 * NN * 64 * 4);   // 16 MB
  float* lpart = (float*)alloc((size_t)8 * NN * 4);
  _Float16* HT = (_Float16*)alloc((size_t)NN * 64 * 2 + 512);
  float* svec  = (float*)alloc(64 * 4);

  prep_kernel<<<256, 256, 0, stream>>>(x, alpha, W1, b1, eta_s, phi_s, H1, HT, svec);
  attn_pass<true><<<2048, 256, 0, stream>>>(eta_s, phi_s, HT, alpha, Ypart, lpart);
  mid_kernel<<<512, 256, 0, stream>>>(Ypart, lpart, H1, wt1, bs1, W2, b2, H2, HT);
  attn_pass<false><<<2048, 256, 0, stream>>>(eta_s, phi_s, HT, alpha, Ypart, nullptr);
  final_kernel<<<512, 256, 0, stream>>>(Ypart, lpart, H2, wt2, bs2, svec);
  out_kernel<<<1, 64, 0, stream>>>(svec, Wl, bl, out);
}

// Round 5
// 170.560 us; speedup vs baseline: 1.3540x; 1.3540x over previous
//
#include <hip/hip_runtime.h>
#include <math.h>

#define NN 8192
#define L2E 1.44269504088896340736f
#define TWO_PI 6.28318530717958647693f

typedef _Float16 h8 __attribute__((ext_vector_type(8)));
typedef _Float16 h4 __attribute__((ext_vector_type(4)));
typedef float f32x4 __attribute__((ext_vector_type(4)));
#define MFMA16(A, B, C) __builtin_amdgcn_mfma_f32_16x16x32_f16(A, B, C, 0, 0, 0)

// async 16B-per-lane global->LDS DMA; LDS dest is wave-uniform base + lane*16
#define GLD_LDS16(gsrc, ldst)                                          \
  __builtin_amdgcn_global_load_lds(                                    \
      (const __attribute__((address_space(1))) unsigned int*)(gsrc),   \
      (__attribute__((address_space(3))) unsigned int*)(ldst), 16, 0, 0)

union V8 { float4 v[2]; float f[8]; };

// ---------------------------------------------------------------------------
// prep: eta_s = eta*s, phi_s = phi*s (s = sqrt(alpha*log2e));
// H1 = relu(x@W1+b1) f32 row-major + f16 transposed [64][NN]. 32 rows/block.
// ---------------------------------------------------------------------------
__global__ __launch_bounds__(256) void prep_kernel(
    const float* __restrict__ x, const float* __restrict__ alpha,
    const float* __restrict__ W1, const float* __restrict__ b1,
    float* __restrict__ eta_s, float* __restrict__ phi_s,
    float* __restrict__ H1, _Float16* __restrict__ HT1,
    float* __restrict__ svec)
{
  __shared__ float sW[448];
  __shared__ float sb[64];
  __shared__ float T[32][65];
  const int t = threadIdx.x;
  if (blockIdx.x == 0 && t < 64) svec[t] = 0.f;
  for (int k = t; k < 448; k += 256) sW[k] = W1[k];
  if (t < 64) sb[t] = b1[t];
  const float s = sqrtf(alpha[0] * L2E);
  const int i0 = blockIdx.x * 32;
  const int r = t >> 3, q = t & 7;
  const int i = i0 + r;
  float xv[7];
#pragma unroll
  for (int k = 0; k < 7; k++) xv[k] = x[i * 7 + k];
  if (q == 0) { eta_s[i] = xv[1] * s; phi_s[i] = xv[2] * s; }
  __syncthreads();
#pragma unroll
  for (int c = 0; c < 8; c++) {
    const int n = q * 8 + c;
    float hv = sb[n];
#pragma unroll
    for (int k = 0; k < 7; k++) hv = fmaf(xv[k], sW[k * 64 + n], hv);
    T[r][n] = fmaxf(hv, 0.f);
  }
  __syncthreads();
  for (int e = t; e < 2048; e += 256) H1[i0 * 64 + e] = T[e >> 6][e & 63];
  const int n = t >> 2, sg = (t & 3) * 8;
  h8 v;
#pragma unroll
  for (int ss = 0; ss < 8; ss++) v[ss] = (_Float16)T[sg + ss][n];
  *(h8*)(HT1 + (size_t)n * NN + i0 + sg) = v;
}

// ---------------------------------------------------------------------------
// attn: 32 i-rows/block, 4-way j-split (grid 1024). 16 stages of 128 j; HT
// chunk [64 rows][128 j] staged via global_load_lds into double-buffered,
// XOR-swizzled LDS. Wave w consumes j-slice w*32..w*32+31 of each stage.
// ---------------------------------------------------------------------------
template <bool NEED_L>
__global__ __launch_bounds__(256, 4) void attn_pass(
    const float* __restrict__ eta_s, const float* __restrict__ phi_s,
    const _Float16* __restrict__ HT, const float* __restrict__ alpha,
    float* __restrict__ Ypart, float* __restrict__ lpart)
{
  __shared__ __align__(16) char smem[33792];
  _Float16* stage = (_Float16*)smem;  // 2 x 16384 B
  const int tid = threadIdx.x;
  const int w = tid >> 6, lane = tid & 63, m = lane & 15, g = lane >> 4;
  const int tile = blockIdx.x >> 2, part = blockIdx.x & 3;
  const int i0 = tile << 5;
  const int jbase = part << 11;
  const float Cs = TWO_PI * sqrtf(alpha[0] * L2E);
  const float et0 = eta_s[i0 + m],      ph0 = phi_s[i0 + m];
  const float et1 = eta_s[i0 + 16 + m], ph1 = phi_s[i0 + 16 + m];

  // staging geometry: slot d = k*256+tid holds HT row (k*16 + tid>>4),
  // swizzled j-group ((tid&15) ^ (tid>>4)). Same swizzle offset for all k.
  const int r0 = tid >> 4, gq = tid & 15;
  const _Float16* sbase = HT + (size_t)r0 * NN + ((gq ^ r0) << 3) + jbase;

  f32x4 a00 = {0,0,0,0}, a01 = {0,0,0,0}, a02 = {0,0,0,0}, a03 = {0,0,0,0};
  f32x4 a10 = {0,0,0,0}, a11 = {0,0,0,0}, a12 = {0,0,0,0}, a13 = {0,0,0,0};
  float l0 = 0.f, l1 = 0.f;

  const float* ep = eta_s + jbase + (w << 5) + (g << 3);
  const float* pp = phi_s + jbase + (w << 5) + (g << 3);
  V8 E, P, En, Pn;
  E.v[0] = *(const float4*)ep;  E.v[1] = *(const float4*)(ep + 4);
  P.v[0] = *(const float4*)pp;  P.v[1] = *(const float4*)(pp + 4);
  En = E; Pn = P;

  // prologue: stage 0 -> buf0
#pragma unroll
  for (int k = 0; k < 4; ++k)
    GLD_LDS16(sbase + (size_t)k * 16 * NN, stage + ((k * 256 + tid) << 3));
  __syncthreads();

  // frag slot (nb=0): row block m, swizzled j-group (w*4+g)^m
  const int fs = ((m << 4) + (((w << 2) | g) ^ m)) << 3;

  union AF { h8 v; decltype(__builtin_amdgcn_cvt_pkrtz(0.f, 0.f)) p[4]; };

  for (int s = 0; s < 16; ++s) {
    _Float16* cur = stage + ((s & 1) << 13);
    if (s < 15) {  // issue async prefetch for s+1 into the other buffer
      _Float16* nxt = stage + (((s + 1) & 1) << 13);
      const _Float16* srcp = sbase + (s + 1) * 128;
#pragma unroll
      for (int k = 0; k < 4; ++k)
        GLD_LDS16(srcp + (size_t)k * 16 * NN, nxt + ((k * 256 + tid) << 3));
      En.v[0] = *(const float4*)(ep + 128); En.v[1] = *(const float4*)(ep + 132);
      Pn.v[0] = *(const float4*)(pp + 128); Pn.v[1] = *(const float4*)(pp + 132);
      ep += 128; pp += 128;
    }
    const h8 b0 = *(const h8*)(cur + fs);
    const h8 b1 = *(const h8*)(cur + 2048 + fs);
    const h8 b2 = *(const h8*)(cur + 4096 + fs);
    const h8 b3 = *(const h8*)(cur + 6144 + fs);

    AF af0, af1;
#pragma unroll
    for (int tt = 0; tt < 8; tt += 2) {
      float Pv[4];
#pragma unroll
      for (int u = 0; u < 2; ++u) {
        {
          const float dp = ph0 - P.f[tt + u];
          const float ad = fabsf(dp);
          const float wr = fminf(ad, Cs - ad);
          const float de = et0 - E.f[tt + u];
          const float r2 = fmaf(de, de, wr * wr);
          const float a  = __builtin_amdgcn_exp2f(-r2);
          const float pv = __builtin_amdgcn_exp2f(fmaf(a, L2E, -L2E));
          if constexpr (NEED_L) l0 += pv;
          Pv[u] = pv;
        }
        {
          const float dp = ph1 - P.f[tt + u];
          const float ad = fabsf(dp);
          const float wr = fminf(ad, Cs - ad);
          const float de = et1 - E.f[tt + u];
          const float r2 = fmaf(de, de, wr * wr);
          const float a  = __builtin_amdgcn_exp2f(-r2);
          const float pv = __builtin_amdgcn_exp2f(fmaf(a, L2E, -L2E));
          if constexpr (NEED_L) l1 += pv;
          Pv[2 + u] = pv;
        }
      }
      af0.p[tt >> 1] = __builtin_amdgcn_cvt_pkrtz(Pv[0], Pv[1]);
      af1.p[tt >> 1] = __builtin_amdgcn_cvt_pkrtz(Pv[2], Pv[3]);
    }
    a00 = MFMA16(af0.v, b0, a00); a01 = MFMA16(af0.v, b1, a01);
    a02 = MFMA16(af0.v, b2, a02); a03 = MFMA16(af0.v, b3, a03);
    a10 = MFMA16(af1.v, b0, a10); a11 = MFMA16(af1.v, b1, a11);
    a12 = MFMA16(af1.v, b2, a12); a13 = MFMA16(af1.v, b3, a13);
    E = En; P = Pn;
    __syncthreads();  // drains prefetch + all frag reads of cur
  }

  // cross-wave reduction (aliases stage; all stage reads completed above).
  // D layout: col = lane&15, row = (lane>>4)*4 + reg.
  typedef float Red2[32][66];
  Red2* red = (Red2*)smem;                  // 2 x 8448 B
  float* lredF = (float*)(smem + 32768);    // [2][4][32]
  const int h = w >> 1;
  if ((w & 1) == 0) {
#pragma unroll
    for (int r = 0; r < 4; ++r) {
      red[h][g * 4 + r][m]      = a00[r]; red[h][g * 4 + r][16 + m] = a01[r];
      red[h][g * 4 + r][32 + m] = a02[r]; red[h][g * 4 + r][48 + m] = a03[r];
      red[h][16 + g * 4 + r][m]      = a10[r]; red[h][16 + g * 4 + r][16 + m] = a11[r];
      red[h][16 + g * 4 + r][32 + m] = a12[r]; red[h][16 + g * 4 + r][48 + m] = a13[r];
    }
    if constexpr (NEED_L) {
      lredF[h * 128 + g * 32 + m] = l0; lredF[h * 128 + g * 32 + 16 + m] = l1;
    }
  }
  __syncthreads();
  if (w & 1) {
#pragma unroll
    for (int r = 0; r < 4; ++r) {
      red[h][g * 4 + r][m]      += a00[r]; red[h][g * 4 + r][16 + m] += a01[r];
      red[h][g * 4 + r][32 + m] += a02[r]; red[h][g * 4 + r][48 + m] += a03[r];
      red[h][16 + g * 4 + r][m]      += a10[r]; red[h][16 + g * 4 + r][16 + m] += a11[r];
      red[h][16 + g * 4 + r][32 + m] += a12[r]; red[h][16 + g * 4 + r][48 + m] += a13[r];
    }
    if constexpr (NEED_L) {
      lredF[h * 128 + g * 32 + m] += l0; lredF[h * 128 + g * 32 + 16 + m] += l1;
    }
  }
  __syncthreads();
#pragma unroll
  for (int k = 0; k < 8; ++k) {
    const int e = tid + k * 256;
    Ypart[((size_t)part * NN + i0 + (e >> 6)) * 64 + (e & 63)] =
        red[0][e >> 6][e & 63] + red[1][e >> 6][e & 63];
  }
  if constexpr (NEED_L) {
    if (tid < 32) {
      float sv = 0.f;
#pragma unroll
      for (int hh = 0; hh < 2; ++hh)
#pragma unroll
        for (int gg = 0; gg < 4; ++gg) sv += lredF[hh * 128 + gg * 32 + tid];
      lpart[(size_t)part * NN + i0 + tid] = sv;
    }
  }
}

// ---------------------------------------------------------------------------
// mid: U = sum(Ypart)/l + H1 ; Z = relu(U@wt1+bs1) ; H2 = relu(Z@W2+b2)
// 16 rows/block, grid 512, f32x4 LDS weight reads.
// ---------------------------------------------------------------------------
__global__ __launch_bounds__(256) void mid_kernel(
    const float* __restrict__ Yp, const float* __restrict__ lp,
    const float* __restrict__ H1, const float* __restrict__ wt1,
    const float* __restrict__ bs1, const float* __restrict__ W2,
    const float* __restrict__ b2, float* __restrict__ H2,
    _Float16* __restrict__ HT2)
{
  __shared__ float sA[64][68];
  __shared__ float sB[64][68];
  __shared__ float U[16][65];
  __shared__ float sb2v[64];
  const int t = threadIdx.x;
  for (int e = t; e < 4096; e += 256) {
    sA[e >> 6][e & 63] = wt1[e];
    sB[e >> 6][e & 63] = W2[e];
  }
  if (t < 64) sb2v[t] = b2[t];
  const float bsv = bs1[0];
  const int i0 = blockIdx.x * 16;
  const int r = t >> 4, q = t & 15;
  const int i = i0 + r;
  float l = 0.f;
#pragma unroll
  for (int p = 0; p < 4; ++p) l += lp[(size_t)p * NN + i];
  const float rl = 1.0f / l;
  f32x4 ya = {0, 0, 0, 0};
#pragma unroll
  for (int p = 0; p < 4; ++p)
    ya += *(const f32x4*)(Yp + ((size_t)p * NN + i) * 64 + q * 4);
  const f32x4 h1 = *(const f32x4*)(H1 + (size_t)i * 64 + q * 4);
#pragma unroll
  for (int c = 0; c < 4; ++c) U[r][q * 4 + c] = fmaf(ya[c], rl, h1[c]);
  __syncthreads();
  float z[4];
#pragma unroll
  for (int c = 0; c < 4; ++c) z[c] = bsv;
  for (int k = 0; k < 64; ++k) {
    const float uk = U[r][k];
    const f32x4 sa = *(const f32x4*)&sA[k][q * 4];
#pragma unroll
    for (int c = 0; c < 4; ++c) z[c] = fmaf(uk, sa[c], z[c]);
  }
  __syncthreads();
#pragma unroll
  for (int c = 0; c < 4; ++c) U[r][q * 4 + c] = fmaxf(z[c], 0.f);
  __syncthreads();
  float hv[4];
#pragma unroll
  for (int c = 0; c < 4; ++c) hv[c] = sb2v[q * 4 + c];
  for (int k = 0; k < 64; ++k) {
    const float uk = U[r][k];
    const f32x4 sb4 = *(const f32x4*)&sB[k][q * 4];
#pragma unroll
    for (int c = 0; c < 4; ++c) hv[c] = fmaf(uk, sb4[c], hv[c]);
  }
  __syncthreads();
#pragma unroll
  for (int c = 0; c < 4; ++c) U[r][q * 4 + c] = fmaxf(hv[c], 0.f);
  __syncthreads();
  for (int e = t; e < 1024; e += 256) H2[i0 * 64 + e] = U[e >> 6][e & 63];
  const int n = t >> 2, sg = (t & 3) * 4;
  h4 v;
#pragma unroll
  for (int ss = 0; ss < 4; ss++) v[ss] = (_Float16)U[sg + ss][n];
  *(h4*)(HT2 + (size_t)n * NN + i0 + sg) = v;
}

// ---------------------------------------------------------------------------
// final: V = relu((sum(Ypart)/l + H2)@wt2 + bs2); column sums -> atomicAdd.
// ---------------------------------------------------------------------------
__global__ __launch_bounds__(256) void final_kernel(
    const float* __restrict__ Yp, const float* __restrict__ lp,
    const float* __restrict__ H2, const float* __restrict__ wt2,
    const float* __restrict__ bs2, float* __restrict__ svec)
{
  __shared__ float sA[64][68];
  __shared__ float U[16][65];
  __shared__ float cred[4][64];
  const int t = threadIdx.x;
  for (int e = t; e < 4096; e += 256) sA[e >> 6][e & 63] = wt2[e];
  const float bsv = bs2[0];
  const int i0 = blockIdx.x * 16;
  const int r = t >> 4, q = t & 15;
  const int i = i0 + r;
  float l = 0.f;
#pragma unroll
  for (int p = 0; p < 4; ++p) l += lp[(size_t)p * NN + i];
  const float rl = 1.0f / l;
  f32x4 ya = {0, 0, 0, 0};
#pragma unroll
  for (int p = 0; p < 4; ++p)
    ya += *(const f32x4*)(Yp + ((size_t)p * NN + i) * 64 + q * 4);
  const f32x4 h2 = *(const f32x4*)(H2 + (size_t)i * 64 + q * 4);
#pragma unroll
  for (int c = 0; c < 4; ++c) U[r][q * 4 + c] = fmaf(ya[c], rl, h2[c]);
  __syncthreads();
  float z[4];
#pragma unroll
  for (int c = 0; c < 4; ++c) z[c] = bsv;
  for (int k = 0; k < 64; ++k) {
    const float uk = U[r][k];
    const f32x4 sa = *(const f32x4*)&sA[k][q * 4];
#pragma unroll
    for (int c = 0; c < 4; ++c) z[c] = fmaf(uk, sa[c], z[c]);
  }
  __syncthreads();
#pragma unroll
  for (int c = 0; c < 4; ++c) U[r][q * 4 + c] = fmaxf(z[c], 0.f);
  __syncthreads();
  const int col = t & 63, rg = t >> 6;
  float ps = 0.f;
#pragma unroll
  for (int rr = 0; rr < 4; rr++) ps += U[rg * 4 + rr][col];
  cred[rg][col] = ps;
  __syncthreads();
  if (t < 64)
    atomicAdd(svec + t, cred[0][t] + cred[1][t] + cred[2][t] + cred[3][t]);
}

__global__ void out_kernel(const float* __restrict__ svec,
                           const float* __restrict__ Wl,
                           const float* __restrict__ bl,
                           float* __restrict__ out)
{
  const int t = threadIdx.x;  // 64 threads
  float v = svec[t] * Wl[t];
#pragma unroll
  for (int off = 32; off > 0; off >>= 1) v += __shfl_down(v, off);
  if (t == 0) {
    const float logit = v + bl[0];
    out[0] = 1.0f / (1.0f + __builtin_amdgcn_exp2f(-logit * L2E));
  }
}

extern "C" void kernel_launch(void* const* d_in, const int* in_sizes, int n_in,
                              void* d_out, int out_size, void* d_ws,
                              size_t ws_size, hipStream_t stream)
{
  const float* x     = (const float*)d_in[0];
  const float* alpha = (const float*)d_in[1];
  const float* W1    = (const float*)d_in[2];
  const float* b1    = (const float*)d_in[3];
  const float* wt1   = (const float*)d_in[4];
  const float* bs1   = (const float*)d_in[5];
  const float* W2    = (const float*)d_in[6];
  const float* b2    = (const float*)d_in[7];
  const float* wt2   = (const float*)d_in[8];
  const float* bs2   = (const float*)d_in[9];
  const float* Wl    = (const float*)d_in[10];
  const float* bl    = (const float*)d_in[11];
  float* out = (float*)d_out;

  char* ws = (char*)d_ws;
  size_t off = 0;
  auto alloc = [&](size_t bytes) {
    void* p = ws + off;
    off = (off + bytes + 255) & ~(size_t)255;
    return p;
  };
  float* eta_s = (float*)alloc(NN * 4 + 256);
  float* phi_s = (float*)alloc(NN * 4 + 256);
  float* H1    = (float*)alloc((size_t)NN * 64 * 4);
  float* H2    = (float*)alloc((size_t)NN * 64 * 4);
  float* Ypart = (float*)alloc((size_t)4 * NN * 64 * 4);   // 8 MB
  float* lpart = (float*)alloc((size_t)4 * NN * 4);
  _Float16* HT = (_Float16*)alloc((size_t)NN * 64 * 2 + 512);
  float* svec  = (float*)alloc(64 * 4);

  prep_kernel<<<256, 256, 0, stream>>>(x, alpha, W1, b1, eta_s, phi_s, H1, HT, svec);
  attn_pass<true><<<1024, 256, 0, stream>>>(eta_s, phi_s, HT, alpha, Ypart, lpart);
  mid_kernel<<<512, 256, 0, stream>>>(Ypart, lpart, H1, wt1, bs1, W2, b2, H2, HT);
  attn_pass<false><<<1024, 256, 0, stream>>>(eta_s, phi_s, HT, alpha, Ypart, nullptr);
  final_kernel<<<512, 256, 0, stream>>>(Ypart, lpart, H2, wt2, bs2, svec);
  out_kernel<<<1, 64, 0, stream>>>(svec, Wl, bl, out);
}